// Round 6
// baseline (3046.534 us; speedup 1.0000x reference)
//
#include <hip/hip_runtime.h>
#include <hip/hip_bf16.h>

#define B   64
#define T   512
#define DIN 64
#define F   64
#define U   128
#define G3  384     // 3U
#define M2  256     // 2U
#define NH  4
#define KD  128
#define HD  512     // NH*KD
#define BT  (B*T)   // 32768

typedef __attribute__((ext_vector_type(8))) short short8;
typedef __attribute__((ext_vector_type(4))) float floatx4;
typedef __hip_bfloat16 bf16;

// ---------------- weight transpose + cast: dst[n][k] = (bf16)src[k][n] ----------------
__global__ __launch_bounds__(256) void k_wcast(const float* __restrict__ src,
        bf16* __restrict__ dst, int K, int N)
{
    const int i = blockIdx.x*256 + threadIdx.x;
    if (i < K*N) {
        const int k = i / N, n = i - k*N;
        dst[n*K + k] = __float2bfloat16(src[i]);
    }
}

// ---------------- conv1d(same,k=3) + BN(inference) + ReLU -> bf16 ----------------
__global__ __launch_bounds__(256) void k_conv(const float* __restrict__ in,
        const float* __restrict__ cw, const float* __restrict__ cb,
        const float* __restrict__ gamma, const float* __restrict__ beta,
        const float* __restrict__ mean, const float* __restrict__ var,
        bf16* __restrict__ x1h)
{
    __shared__ float w_s[3*64*64];   // 48 KB
    __shared__ float in_s[18*64];
    const int b  = blockIdx.y;
    const int t0 = blockIdx.x * 16;
    const int tid = threadIdx.x;
    for (int idx = tid; idx < 3*64*64; idx += 256) w_s[idx] = cw[idx];
    for (int idx = tid; idx < 18*64; idx += 256) {
        int row = idx >> 6;
        int d   = idx & 63;
        int t   = t0 - 1 + row;
        in_s[idx] = (t >= 0 && t < T) ? in[((size_t)b*T + t)*DIN + d] : 0.0f;
    }
    __syncthreads();
    const int f  = tid & 63;
    const int tl = tid >> 6;   // 0..3
    const float scale = gamma[f] * rsqrtf(var[f] + 1e-3f);
    const float shift = beta[f] - mean[f] * scale;
    const float bias  = cb[f];
    for (int q = 0; q < 4; ++q) {
        const int tt = tl*4 + q;   // 0..15
        float acc = bias;
        for (int tap = 0; tap < 3; ++tap) {
            const float* irow = &in_s[(tt + tap)*64];
            const float* wrow = &w_s[tap*64*64 + f];
            #pragma unroll 16
            for (int d = 0; d < 64; ++d) acc += irow[d] * wrow[d*64];
        }
        float v = acc * scale + shift;
        x1h[((size_t)b*T + t0 + tt)*F + f] = __float2bfloat16(fmaxf(v, 0.0f));
    }
}

// ------------- MFMA bf16 GEMM: C[R,N] = A[R,K] @ Bt[N,K]^T + bias (+resid) -------------
__global__ __launch_bounds__(256) void k_gemm(const bf16* __restrict__ A,
        const bf16* __restrict__ Bt, const float* __restrict__ bias,
        const bf16* __restrict__ resid, float* __restrict__ outF,
        bf16* __restrict__ outH, int K, int N, int biasRow)
{
    __shared__ short As[128*32];   // 8 KB
    __shared__ short Bs[128*32];   // 8 KB
    const int nbase = blockIdx.x * 128;
    const int rbase = blockIdx.y * 128;
    const int tid  = threadIdx.x;
    const int lane = tid & 63;
    const int wv   = tid >> 6;
    const int wm   = wv & 1;        // row half
    const int wn   = wv >> 1;       // col half
    const int l16  = lane & 15;
    const int quad = lane >> 4;

    floatx4 acc[4][4];
    #pragma unroll
    for (int i = 0; i < 4; ++i)
        #pragma unroll
        for (int j = 0; j < 4; ++j) acc[i][j] = (floatx4)0.0f;

    const int row  = tid >> 1;           // staging: 2 threads per tile-row
    const int koff = (tid & 1) * 16;     // 16 bf16 = 32 B per thread
    const int nK = K >> 5;
    for (int kt = 0; kt < nK; ++kt) {
        if (kt) __syncthreads();
        {
            const float4* ga = reinterpret_cast<const float4*>(
                &A[(size_t)(rbase + row)*K + kt*32 + koff]);
            const float4 a0 = ga[0], a1 = ga[1];
            const float4* gb = reinterpret_cast<const float4*>(
                &Bt[(size_t)(nbase + row)*K + kt*32 + koff]);
            const float4 b0 = gb[0], b1 = gb[1];
            float4* la = reinterpret_cast<float4*>(&As[row*32 + koff]);
            la[0] = a0; la[1] = a1;
            float4* lb = reinterpret_cast<float4*>(&Bs[row*32 + koff]);
            lb[0] = b0; lb[1] = b1;
        }
        __syncthreads();
        short8 af[4], bf[4];
        #pragma unroll
        for (int i = 0; i < 4; ++i)
            af[i] = *reinterpret_cast<const short8*>(&As[(wm*64 + i*16 + l16)*32 + quad*8]);
        #pragma unroll
        for (int j = 0; j < 4; ++j)
            bf[j] = *reinterpret_cast<const short8*>(&Bs[(wn*64 + j*16 + l16)*32 + quad*8]);
        #pragma unroll
        for (int i = 0; i < 4; ++i)
            #pragma unroll
            for (int j = 0; j < 4; ++j)
                acc[i][j] = __builtin_amdgcn_mfma_f32_16x16x32_bf16(af[i], bf[j], acc[i][j], 0, 0, 0);
    }

    #pragma unroll
    for (int j = 0; j < 4; ++j) {
        const int gcol = nbase + wn*64 + j*16 + l16;
        const float bj = biasRow ? 0.0f : bias[gcol];
        #pragma unroll
        for (int i = 0; i < 4; ++i) {
            #pragma unroll
            for (int r = 0; r < 4; ++r) {
                const int grow = rbase + wm*64 + i*16 + quad*4 + r;
                const size_t off = (size_t)grow*N + gcol;
                float v = acc[i][j][r] + (biasRow ? bias[grow] : bj);
                if (resid) v += __bfloat162float(resid[off]);
                if (outF) outF[off] = v;
                if (outH) outH[off] = __float2bfloat16(v);
            }
        }
    }
}

// ---------------- MFMA-batched GRU scan ----------------
__device__ __forceinline__ float sigmoidf_(float x){ return 1.0f/(1.0f + __expf(-x)); }
__device__ __forceinline__ float tanhf_(float x){ return 2.0f/(1.0f + __expf(-2.0f*x)) - 1.0f; }
__device__ __forceinline__ float xload(const float* p){ return *p; }
__device__ __forceinline__ float xload(const bf16* p){ return __bfloat162float(*p); }
__device__ __forceinline__ unsigned bf16bits(float x){
    bf16 h = __float2bfloat16(x);
    return (unsigned)*reinterpret_cast<unsigned short*>(&h);
}

// Block = 16 batches x 1 direction (grid 4x2), 512 threads = 8 waves.
// h ping-pongs through LDS in MFMA A-frag FRAGMENT ORDER:
//   element (m=batch, c=col) at short addr (c>>3)*128 + m*8 + (c&7)
//   -> read: lane reads 16 B at 16*(kt*64 + lane): lane-contiguous, ZERO conflicts
//   -> write: lanes pair via shfl_xor(1), even lane writes b32 (cols c,c+1): 4-way max
// xg: depth-2 register prefetch pipeline (loads for t+2 issued at top of step t).
template<typename XT>
__global__ __launch_bounds__(512, 1) void k_gru(const XT* __restrict__ xg_f,
        const XT* __restrict__ xg_b, const float* __restrict__ wh_f,
        const float* __restrict__ wh_b, const float* __restrict__ b_f,
        const float* __restrict__ b_b, bf16* __restrict__ yseq,
        float* __restrict__ hout)
{
    const int dir   = blockIdx.y;
    const int bbase = blockIdx.x * 16;
    const XT* xg = dir ? xg_b : xg_f;               // [B*T, 3U]
    const float* wh = dir ? wh_b : wh_f;            // [U, 3U]
    const float* bh = (dir ? b_b : b_f) + G3;       // b[1]
    const int tid  = threadIdx.x;
    const int lane = tid & 63;
    const int wv   = tid >> 6;       // 0..7
    const int l16  = lane & 15;
    const int quad = lane >> 4;
    const int jcol = wv*16 + l16;    // unit column 0..127

    // recurrent-weight B-frags, register-resident: [gate][kt]
    short8 wfrag[3][4];
    #pragma unroll
    for (int g = 0; g < 3; ++g)
        #pragma unroll
        for (int kt = 0; kt < 4; ++kt)
            #pragma unroll
            for (int j = 0; j < 8; ++j)
                reinterpret_cast<bf16*>(&wfrag[g][kt])[j] = __float2bfloat16(
                    wh[(size_t)(kt*32 + quad*8 + j)*G3 + g*U + jcol]);

    const float bhz = bh[        jcol];
    const float bhr = bh[U     + jcol];
    const float bhn = bh[2*U   + jcol];

    __shared__ __align__(16) short hbuf[2][2048];   // 4 KB each, fragment order
    for (int i = tid; i < 2*2048; i += 512) (&hbuf[0][0])[i] = 0;
    __syncthreads();

    float hprev[4] = {0.f, 0.f, 0.f, 0.f};   // h_old for batches quad*4+r

    // depth-2 xg prefetch pipeline
    float pxz[2][4], pxr[2][4], pxn[2][4];
    #pragma unroll
    for (int s = 0; s < 2; ++s) {
        const int tt = dir ? (T-1-s) : s;
        #pragma unroll
        for (int r = 0; r < 4; ++r) {
            const size_t ro = ((size_t)(bbase + quad*4 + r)*T + tt)*G3;
            pxz[s][r] = xload(&xg[ro +       jcol]);
            pxr[s][r] = xload(&xg[ro + U   + jcol]);
            pxn[s][r] = xload(&xg[ro + 2*U + jcol]);
        }
    }

    for (int step = 0; step < T; ++step) {
        const int t = dir ? (T-1-step) : step;
        const int s = step & 1;
        // drain pipeline slot (loads issued 2 steps ago), then refill for t+2
        float uz[4], ur[4], un[4];
        #pragma unroll
        for (int r = 0; r < 4; ++r) { uz[r]=pxz[s][r]; ur[r]=pxr[s][r]; un[r]=pxn[s][r]; }
        if (step + 2 < T) {
            const int tn = dir ? (T-3-step) : (step+2);
            #pragma unroll
            for (int r = 0; r < 4; ++r) {
                const size_t ro = ((size_t)(bbase + quad*4 + r)*T + tn)*G3;
                pxz[s][r] = xload(&xg[ro +       jcol]);
                pxr[s][r] = xload(&xg[ro + U   + jcol]);
                pxn[s][r] = xload(&xg[ro + 2*U + jcol]);
            }
        }
        // h A-frags: lane-contiguous b128, conflict-free
        short8 hfrag[4];
        #pragma unroll
        for (int kt = 0; kt < 4; ++kt)
            hfrag[kt] = *reinterpret_cast<const short8*>(&hbuf[s][(kt*64 + lane)*8]);
        floatx4 az = (floatx4)0.f, ar = (floatx4)0.f, an = (floatx4)0.f;
        #pragma unroll
        for (int kt = 0; kt < 4; ++kt) {
            az = __builtin_amdgcn_mfma_f32_16x16x32_bf16(hfrag[kt], wfrag[0][kt], az, 0, 0, 0);
            ar = __builtin_amdgcn_mfma_f32_16x16x32_bf16(hfrag[kt], wfrag[1][kt], ar, 0, 0, 0);
            an = __builtin_amdgcn_mfma_f32_16x16x32_bf16(hfrag[kt], wfrag[2][kt], an, 0, 0, 0);
        }
        // gates + state update (batch = quad*4+r, col = jcol)
        #pragma unroll
        for (int r = 0; r < 4; ++r) {
            const float z  = sigmoidf_(uz[r] + az[r] + bhz);
            const float rr = sigmoidf_(ur[r] + ar[r] + bhr);
            const float n  = tanhf_(un[r] + rr*(an[r] + bhn));
            const float hnew = z*hprev[r] + (1.0f - z)*n;
            hprev[r] = hnew;
            // paired b32 LDS write (cols jcol, jcol^1)
            const unsigned my = bf16bits(hnew);
            const unsigned ot = (unsigned)__shfl_xor((int)my, 1);
            if (!(l16 & 1)) {
                const int c = jcol;   // even
                *reinterpret_cast<unsigned*>(
                    &hbuf[s^1][(c>>3)*128 + (quad*4+r)*8 + (c&7)]) = my | (ot << 16);
            }
            if (yseq)
                yseq[((size_t)(bbase + quad*4 + r)*T + t)*M2 + dir*U + jcol] =
                    __float2bfloat16(hnew);
        }
        __syncthreads();
    }
    if (hout) {
        #pragma unroll
        for (int r = 0; r < 4; ++r)
            hout[(size_t)(bbase + quad*4 + r)*M2 + dir*U + jcol] = hprev[r];
    }
}

// ---------------- MFMA flash attention ----------------
// Q,K,O: [B*T, HD] bf16 (head h at col h*KD). VT: [HD, B*T] bf16 (transposed V).
__global__ __launch_bounds__(256) void k_attn(const bf16* __restrict__ Q,
        const bf16* __restrict__ Kp, const bf16* __restrict__ VT,
        bf16* __restrict__ O)
{
    __shared__ short k_s[64*136];    // 17408 B
    __shared__ short vt_s[128*72];   // 18432 B
    __shared__ short p_s[64*72];     //  9216 B
    const int qt = blockIdx.x;       // 0..7
    const int b  = blockIdx.y;
    const int h  = blockIdx.z;
    const int tid  = threadIdx.x;
    const int lane = tid & 63;
    const int wv   = tid >> 6;
    const int l16  = lane & 15;
    const int quad = lane >> 4;

    short8 qfrag[4];
    {
        const size_t qoff = (size_t)(b*T + qt*64 + wv*16 + l16)*HD + h*KD + quad*8;
        #pragma unroll
        for (int kt = 0; kt < 4; ++kt)
            qfrag[kt] = *reinterpret_cast<const short8*>(&Q[qoff + kt*32]);
    }

    floatx4 Oa[8];
    #pragma unroll
    for (int nf = 0; nf < 8; ++nf) Oa[nf] = (floatx4)0.0f;
    float mrun = -1e30f, lrun = 0.0f;

    for (int kg = 0; kg < 8; ++kg) {
        __syncthreads();
        #pragma unroll
        for (int it = 0; it < 4; ++it) {
            const int linear = it*256 + tid;
            const int key = linear >> 4;
            const int dc  = linear & 15;
            const float4 v = *reinterpret_cast<const float4*>(
                &Kp[(size_t)(b*T + kg*64 + key)*HD + h*KD + dc*8]);
            *reinterpret_cast<float4*>(&k_s[key*136 + dc*8]) = v;
        }
        #pragma unroll
        for (int it = 0; it < 4; ++it) {
            const int linear = it*256 + tid;
            const int d  = linear >> 3;
            const int kc = linear & 7;
            const float4 v = *reinterpret_cast<const float4*>(
                &VT[(size_t)(h*KD + d)*BT + b*T + kg*64 + kc*8]);
            *reinterpret_cast<float4*>(&vt_s[d*72 + kc*8]) = v;
        }
        __syncthreads();
        floatx4 s[4];
        #pragma unroll
        for (int kb = 0; kb < 4; ++kb) s[kb] = (floatx4)0.0f;
        #pragma unroll
        for (int kt = 0; kt < 4; ++kt) {
            #pragma unroll
            for (int kb = 0; kb < 4; ++kb) {
                const short8 af = *reinterpret_cast<const short8*>(
                    &k_s[(kb*16 + l16)*136 + kt*32 + quad*8]);
                s[kb] = __builtin_amdgcn_mfma_f32_16x16x32_bf16(af, qfrag[kt], s[kb], 0, 0, 0);
            }
        }
        float kmax = -1e30f;
        #pragma unroll
        for (int kb = 0; kb < 4; ++kb)
            #pragma unroll
            for (int r = 0; r < 4; ++r) {
                s[kb][r] *= 0.08838834764831845f;
                kmax = fmaxf(kmax, s[kb][r]);
            }
        kmax = fmaxf(kmax, __shfl_xor(kmax, 16));
        kmax = fmaxf(kmax, __shfl_xor(kmax, 32));
        const float mnew  = fmaxf(mrun, kmax);
        const float alpha = __expf(mrun - mnew);
        float psum = 0.0f;
        #pragma unroll
        for (int kb = 0; kb < 4; ++kb)
            #pragma unroll
            for (int r = 0; r < 4; ++r) {
                const float p = __expf(s[kb][r] - mnew);
                s[kb][r] = p;
                psum += p;
            }
        psum += __shfl_xor(psum, 16);
        psum += __shfl_xor(psum, 32);
        lrun = lrun*alpha + psum;
        mrun = mnew;
        #pragma unroll
        for (int r = 0; r < 4; ++r) {
            const float ar = __shfl(alpha, quad*4 + r);
            #pragma unroll
            for (int nf = 0; nf < 8; ++nf) Oa[nf][r] *= ar;
        }
        bf16* pb = reinterpret_cast<bf16*>(p_s);
        #pragma unroll
        for (int kb = 0; kb < 4; ++kb)
            #pragma unroll
            for (int r = 0; r < 4; ++r)
                pb[(wv*16 + l16)*72 + kb*16 + quad*4 + r] = __float2bfloat16(s[kb][r]);
        #pragma unroll
        for (int kt2 = 0; kt2 < 2; ++kt2) {
            const short8 pf = *reinterpret_cast<const short8*>(
                &p_s[(wv*16 + l16)*72 + kt2*32 + quad*8]);
            #pragma unroll
            for (int nf = 0; nf < 8; ++nf) {
                const short8 vf = *reinterpret_cast<const short8*>(
                    &vt_s[(nf*16 + l16)*72 + kt2*32 + quad*8]);
                Oa[nf] = __builtin_amdgcn_mfma_f32_16x16x32_bf16(pf, vf, Oa[nf], 0, 0, 0);
            }
        }
    }
    float linv[4];
    #pragma unroll
    for (int r = 0; r < 4; ++r) linv[r] = 1.0f / __shfl(lrun, quad*4 + r);
    #pragma unroll
    for (int nf = 0; nf < 8; ++nf)
        #pragma unroll
        for (int r = 0; r < 4; ++r) {
            const size_t row = (size_t)(b*T + qt*64 + wv*16 + quad*4 + r);
            O[row*HD + h*KD + nf*16 + l16] = __float2bfloat16(Oa[nf][r] * linv[r]);
        }
}

// ---------------- dense head ----------------
__global__ void k_dense(const float* __restrict__ h2, const float* __restrict__ dw,
                        const float* __restrict__ db, float* __restrict__ out)
{
    const int b = threadIdx.x;
    float acc = db[0];
    for (int mm = 0; mm < M2; ++mm) acc += h2[b*M2 + mm] * dw[mm];
    out[b] = acc;
}

extern "C" void kernel_launch(void* const* d_in, const int* in_sizes, int n_in,
                              void* d_out, int out_size, void* d_ws, size_t ws_size,
                              hipStream_t stream)
{
    const float* inputs  = (const float*)d_in[0];
    const float* conv_w  = (const float*)d_in[1];
    const float* conv_b  = (const float*)d_in[2];
    const float* bn_g    = (const float*)d_in[3];
    const float* bn_b    = (const float*)d_in[4];
    const float* bn_m    = (const float*)d_in[5];
    const float* bn_v    = (const float*)d_in[6];
    const float* g1f_wx  = (const float*)d_in[7];
    const float* g1f_wh  = (const float*)d_in[8];
    const float* g1f_b   = (const float*)d_in[9];
    const float* g1b_wx  = (const float*)d_in[10];
    const float* g1b_wh  = (const float*)d_in[11];
    const float* g1b_b   = (const float*)d_in[12];
    const float* wq      = (const float*)d_in[13];
    const float* bq      = (const float*)d_in[14];
    const float* wk      = (const float*)d_in[15];
    const float* bk      = (const float*)d_in[16];
    const float* wv_     = (const float*)d_in[17];
    const float* bv      = (const float*)d_in[18];
    const float* wo      = (const float*)d_in[19];
    const float* bo      = (const float*)d_in[20];
    const float* g2f_wx  = (const float*)d_in[21];
    const float* g2f_wh  = (const float*)d_in[22];
    const float* g2f_b   = (const float*)d_in[23];
    const float* g2b_wx  = (const float*)d_in[24];
    const float* g2b_wh  = (const float*)d_in[25];
    const float* g2b_b   = (const float*)d_in[26];
    const float* dense_w = (const float*)d_in[27];
    const float* dense_b = (const float*)d_in[28];
    float* out = (float*)d_out;
    (void)in_sizes; (void)n_in; (void)out_size; (void)ws_size;

    // ---- workspace (float-slot offsets into 128 MiB = 33,554,432 fslots) ----
    float* ws = (float*)d_ws;
    bf16* wb = (bf16*)ws;
    bf16* g1fT = wb;            // [384,64]
    bf16* g1bT = wb + 24576;
    bf16* wqT  = wb + 49152;    // [512,256]
    bf16* wkT  = wb + 180224;
    bf16* wvT  = wb + 311296;   // [512,256] -> GEMM-A for V^T
    bf16* woT  = wb + 442368;   // [256,512]
    bf16* g2fT = wb + 573440;   // [384,256]
    bf16* g2bT = wb + 671744;   // ends 770048 < 786432

    bf16*  x1h  = (bf16*)(ws + 393216);     // [B*T,64]
    float* xg1f = ws + 1441792;             // [B*T,384] fp32
    float* xg1b = ws + 14024704;            // [B*T,384] fp32
    bf16*  y1h  = (bf16*)(ws + 26607616);   // [B*T,256]
    bf16*  qh   = (bf16*)(ws + 393216);     // [B*T,512]
    bf16*  kh   = (bf16*)(ws + 8781824);    // [B*T,512]
    bf16*  vtg  = (bf16*)(ws + 17170432);   // [512, B*T]
    bf16*  Oh   = qh;                       // attention output in-place
    bf16*  x2h  = (bf16*)(ws + 17170432);   // [B*T,256] (over dead vtg)
    bf16*  xg2f = (bf16*)(ws + 393216);     // [B*T,384]
    bf16*  xg2b = (bf16*)(ws + 6684672);
    float* h2   = ws + 12976128;            // [B,256]

    // 0. weight casts
    k_wcast<<<(64*384+255)/256, 256, 0, stream>>>(g1f_wx, g1fT, 64, 384);
    k_wcast<<<(64*384+255)/256, 256, 0, stream>>>(g1b_wx, g1bT, 64, 384);
    k_wcast<<<(256*512+255)/256, 256, 0, stream>>>(wq,  wqT, 256, 512);
    k_wcast<<<(256*512+255)/256, 256, 0, stream>>>(wk,  wkT, 256, 512);
    k_wcast<<<(256*512+255)/256, 256, 0, stream>>>(wv_, wvT, 256, 512);
    k_wcast<<<(512*256+255)/256, 256, 0, stream>>>(wo,  woT, 512, 256);
    k_wcast<<<(256*384+255)/256, 256, 0, stream>>>(g2f_wx, g2fT, 256, 384);
    k_wcast<<<(256*384+255)/256, 256, 0, stream>>>(g2b_wx, g2bT, 256, 384);

    // 1. conv + BN + ReLU -> x1h
    k_conv<<<dim3(T/16, B), 256, 0, stream>>>(inputs, conv_w, conv_b,
                                              bn_g, bn_b, bn_m, bn_v, x1h);
    // 2. GRU1 input gates (fp32)
    k_gemm<<<dim3(3, 256), 256, 0, stream>>>(x1h, g1fT, g1f_b, nullptr, xg1f, nullptr, 64, G3, 0);
    k_gemm<<<dim3(3, 256), 256, 0, stream>>>(x1h, g1bT, g1b_b, nullptr, xg1b, nullptr, 64, G3, 0);
    // 3. GRU1 scan -> y1h  (MFMA-batched, 8 blocks x 512)
    k_gru<float><<<dim3(4, 2), 512, 0, stream>>>(xg1f, xg1b, g1f_wh, g1b_wh,
                                                 g1f_b, g1b_b, y1h, nullptr);
    // 4. Q,K projections; V as transposed GEMM
    k_gemm<<<dim3(4, 256), 256, 0, stream>>>(y1h, wqT, bq, nullptr, nullptr, qh, 256, HD, 0);
    k_gemm<<<dim3(4, 256), 256, 0, stream>>>(y1h, wkT, bk, nullptr, nullptr, kh, 256, HD, 0);
    k_gemm<<<dim3(BT/128, 4), 256, 0, stream>>>(wvT, y1h, bv, nullptr, nullptr, vtg, 256, BT, 1);
    // 5. MFMA flash attention, O in-place over Q
    k_attn<<<dim3(T/64, B, NH), 256, 0, stream>>>(qh, kh, vtg, Oh);
    // 6. output projection + bias + residual(y1h) -> x2h
    k_gemm<<<dim3(2, 256), 256, 0, stream>>>(Oh, woT, bo, y1h, nullptr, x2h, HD, M2, 0);
    // 7. GRU2 input gates (bf16)
    k_gemm<<<dim3(3, 256), 256, 0, stream>>>(x2h, g2fT, g2f_b, nullptr, nullptr, xg2f, 256, G3, 0);
    k_gemm<<<dim3(3, 256), 256, 0, stream>>>(x2h, g2bT, g2b_b, nullptr, nullptr, xg2b, 256, G3, 0);
    // 8. GRU2 scan -> h2
    k_gru<bf16><<<dim3(4, 2), 512, 0, stream>>>(xg2f, xg2b, g2f_wh, g2b_wh,
                                                g2f_b, g2b_b, nullptr, h2);
    // 9. dense head
    k_dense<<<1, 64, 0, stream>>>(h2, dense_w, dense_b, out);
}

// Round 7
// 1600.304 us; speedup vs baseline: 1.9037x; 1.9037x over previous
//
#include <hip/hip_runtime.h>
#include <hip/hip_bf16.h>

#define B   64
#define T   512
#define DIN 64
#define F   64
#define U   128
#define G3  384     // 3U
#define M2  256     // 2U
#define NH  4
#define KD  128
#define HD  512     // NH*KD
#define BT  (B*T)   // 32768

typedef __attribute__((ext_vector_type(8))) short short8;
typedef __attribute__((ext_vector_type(4))) float floatx4;
typedef __attribute__((ext_vector_type(4))) unsigned short ushort4_t;
typedef __hip_bfloat16 bf16;

// ---------------- weight transpose + cast: dst[n][k] = (bf16)src[k][n] ----------------
__global__ __launch_bounds__(256) void k_wcast(const float* __restrict__ src,
        bf16* __restrict__ dst, int K, int N)
{
    const int i = blockIdx.x*256 + threadIdx.x;
    if (i < K*N) {
        const int k = i / N, n = i - k*N;
        dst[n*K + k] = __float2bfloat16(src[i]);
    }
}

// ---------------- conv1d(same,k=3) + BN(inference) + ReLU -> bf16 ----------------
__global__ __launch_bounds__(256) void k_conv(const float* __restrict__ in,
        const float* __restrict__ cw, const float* __restrict__ cb,
        const float* __restrict__ gamma, const float* __restrict__ beta,
        const float* __restrict__ mean, const float* __restrict__ var,
        bf16* __restrict__ x1h)
{
    __shared__ float w_s[3*64*64];   // 48 KB
    __shared__ float in_s[18*64];
    const int b  = blockIdx.y;
    const int t0 = blockIdx.x * 16;
    const int tid = threadIdx.x;
    for (int idx = tid; idx < 3*64*64; idx += 256) w_s[idx] = cw[idx];
    for (int idx = tid; idx < 18*64; idx += 256) {
        int row = idx >> 6;
        int d   = idx & 63;
        int t   = t0 - 1 + row;
        in_s[idx] = (t >= 0 && t < T) ? in[((size_t)b*T + t)*DIN + d] : 0.0f;
    }
    __syncthreads();
    const int f  = tid & 63;
    const int tl = tid >> 6;   // 0..3
    const float scale = gamma[f] * rsqrtf(var[f] + 1e-3f);
    const float shift = beta[f] - mean[f] * scale;
    const float bias  = cb[f];
    for (int q = 0; q < 4; ++q) {
        const int tt = tl*4 + q;   // 0..15
        float acc = bias;
        for (int tap = 0; tap < 3; ++tap) {
            const float* irow = &in_s[(tt + tap)*64];
            const float* wrow = &w_s[tap*64*64 + f];
            #pragma unroll 16
            for (int d = 0; d < 64; ++d) acc += irow[d] * wrow[d*64];
        }
        float v = acc * scale + shift;
        x1h[((size_t)b*T + t0 + tt)*F + f] = __float2bfloat16(fmaxf(v, 0.0f));
    }
}

// ------------- MFMA bf16 GEMM: C[R,N] = A[R,K] @ Bt[N,K]^T + bias (+resid) -------------
__global__ __launch_bounds__(256) void k_gemm(const bf16* __restrict__ A,
        const bf16* __restrict__ Bt, const float* __restrict__ bias,
        const bf16* __restrict__ resid, float* __restrict__ outF,
        bf16* __restrict__ outH, int K, int N, int biasRow)
{
    __shared__ short As[128*32];   // 8 KB
    __shared__ short Bs[128*32];   // 8 KB
    const int nbase = blockIdx.x * 128;
    const int rbase = blockIdx.y * 128;
    const int tid  = threadIdx.x;
    const int lane = tid & 63;
    const int wv   = tid >> 6;
    const int wm   = wv & 1;        // row half
    const int wn   = wv >> 1;       // col half
    const int l16  = lane & 15;
    const int quad = lane >> 4;

    floatx4 acc[4][4];
    #pragma unroll
    for (int i = 0; i < 4; ++i)
        #pragma unroll
        for (int j = 0; j < 4; ++j) acc[i][j] = (floatx4)0.0f;

    const int row  = tid >> 1;           // staging: 2 threads per tile-row
    const int koff = (tid & 1) * 16;     // 16 bf16 = 32 B per thread
    const int nK = K >> 5;
    for (int kt = 0; kt < nK; ++kt) {
        if (kt) __syncthreads();
        {
            const float4* ga = reinterpret_cast<const float4*>(
                &A[(size_t)(rbase + row)*K + kt*32 + koff]);
            const float4 a0 = ga[0], a1 = ga[1];
            const float4* gb = reinterpret_cast<const float4*>(
                &Bt[(size_t)(nbase + row)*K + kt*32 + koff]);
            const float4 b0 = gb[0], b1 = gb[1];
            float4* la = reinterpret_cast<float4*>(&As[row*32 + koff]);
            la[0] = a0; la[1] = a1;
            float4* lb = reinterpret_cast<float4*>(&Bs[row*32 + koff]);
            lb[0] = b0; lb[1] = b1;
        }
        __syncthreads();
        short8 af[4], bf[4];
        #pragma unroll
        for (int i = 0; i < 4; ++i)
            af[i] = *reinterpret_cast<const short8*>(&As[(wm*64 + i*16 + l16)*32 + quad*8]);
        #pragma unroll
        for (int j = 0; j < 4; ++j)
            bf[j] = *reinterpret_cast<const short8*>(&Bs[(wn*64 + j*16 + l16)*32 + quad*8]);
        #pragma unroll
        for (int i = 0; i < 4; ++i)
            #pragma unroll
            for (int j = 0; j < 4; ++j)
                acc[i][j] = __builtin_amdgcn_mfma_f32_16x16x32_bf16(af[i], bf[j], acc[i][j], 0, 0, 0);
    }

    #pragma unroll
    for (int j = 0; j < 4; ++j) {
        const int gcol = nbase + wn*64 + j*16 + l16;
        const float bj = biasRow ? 0.0f : bias[gcol];
        #pragma unroll
        for (int i = 0; i < 4; ++i) {
            #pragma unroll
            for (int r = 0; r < 4; ++r) {
                const int grow = rbase + wm*64 + i*16 + quad*4 + r;
                const size_t off = (size_t)grow*N + gcol;
                float v = acc[i][j][r] + (biasRow ? bias[grow] : bj);
                if (resid) v += __bfloat162float(resid[off]);
                if (outF) outF[off] = v;
                if (outH) outH[off] = __float2bfloat16(v);
            }
        }
    }
}

// ---------------- MFMA-batched GRU scan (transposed formulation) ----------------
__device__ __forceinline__ float sigmoidf_(float x){ return 1.0f/(1.0f + __expf(-x)); }
__device__ __forceinline__ float tanhf_(float x){ return 2.0f/(1.0f + __expf(-2.0f*x)) - 1.0f; }
__device__ __forceinline__ float bfbits2f(unsigned short u){
    return __uint_as_float(((unsigned)u) << 16);
}

// Block = 16 batches x 1 direction (grid 4x2), 512 threads = 8 waves.
// Computes hg^T = W^T (A, regs) . H^T (B, LDS): C gives lane (quad,l16) the gates
// for batch l16 at 4 consecutive cols cb=wv*16+quad*4 .. +4:
//   -> hnew LDS write = one contiguous b64 (<=2-way banks)
//   -> xg load = 3 x b64 vector loads per step
//   -> hprev self-aligned in registers across steps
// h layout in LDS: h[batch][col], stride 136 shorts -> B-frag b128 reads contiguous.
// Barrier = s_waitcnt lgkmcnt(0) + raw s_barrier (NO vmcnt drain): xg prefetch
// (depth 2, statically indexed regs) and yseq stores stay in flight across steps.
__global__ __launch_bounds__(512, 2) void k_gru(const bf16* __restrict__ xg_f,
        const bf16* __restrict__ xg_b, const float* __restrict__ wh_f,
        const float* __restrict__ wh_b, const float* __restrict__ b_f,
        const float* __restrict__ b_b, bf16* __restrict__ yseq,
        float* __restrict__ hout)
{
    const int dir   = blockIdx.y;
    const int bbase = blockIdx.x * 16;
    const bf16* xg  = dir ? xg_b : xg_f;            // [B*T, 3U]
    const float* wh = dir ? wh_b : wh_f;            // [U, 3U]
    const float* bh = (dir ? b_b : b_f) + G3;       // b[1]
    const int tid  = threadIdx.x;
    const int lane = tid & 63;
    const int wv   = tid >> 6;       // 0..7
    const int l16  = lane & 15;
    const int quad = lane >> 4;
    const int cb   = wv*16 + quad*4; // this lane's 4 gate cols
    const int brow = bbase + l16;    // this lane's batch

    // W^T A-frags, register-resident: A[m=l16][k=quad*8+j] per (gate, kt)
    short8 wfrag[3][4];
    #pragma unroll
    for (int g = 0; g < 3; ++g)
        #pragma unroll
        for (int kt = 0; kt < 4; ++kt)
            #pragma unroll
            for (int j = 0; j < 8; ++j)
                reinterpret_cast<bf16*>(&wfrag[g][kt])[j] = __float2bfloat16(
                    wh[(size_t)(kt*32 + quad*8 + j)*G3 + g*U + wv*16 + l16]);

    float bz[4], br_[4], bn_[4];
    #pragma unroll
    for (int r = 0; r < 4; ++r) {
        bz[r]  = bh[      cb + r];
        br_[r] = bh[U   + cb + r];
        bn_[r] = bh[2*U + cb + r];
    }

    __shared__ __align__(16) short hbuf[2][16*136];   // h[b][c] bf16, stride 136
    for (int i = tid; i < 2*16*136; i += 512) (&hbuf[0][0])[i] = 0;
    __syncthreads();

    float hprev[4] = {0.f, 0.f, 0.f, 0.f};

    // depth-2 xg prefetch (statically indexed: unroll-2 body, slot = u)
    ushort4_t xs[2][3];
    #pragma unroll
    for (int s = 0; s < 2; ++s) {
        const int tt = dir ? (T-1-s) : s;
        const size_t ro = ((size_t)brow*T + tt)*G3;
        xs[s][0] = *reinterpret_cast<const ushort4_t*>(&xg[ro +       cb]);
        xs[s][1] = *reinterpret_cast<const ushort4_t*>(&xg[ro + U   + cb]);
        xs[s][2] = *reinterpret_cast<const ushort4_t*>(&xg[ro + 2*U + cb]);
    }

    for (int step2 = 0; step2 < T; step2 += 2) {
        #pragma unroll
        for (int u = 0; u < 2; ++u) {
            const int step = step2 + u;
            const int t = dir ? (T-1-step) : step;
            // h B-frags: contiguous b128, bank-balanced
            short8 hfrag[4];
            #pragma unroll
            for (int kt = 0; kt < 4; ++kt)
                hfrag[kt] = *reinterpret_cast<const short8*>(
                    &hbuf[u][l16*136 + kt*32 + quad*8]);
            // acc preloaded with recurrent bias
            floatx4 az, ar, an;
            #pragma unroll
            for (int r = 0; r < 4; ++r) { az[r]=bz[r]; ar[r]=br_[r]; an[r]=bn_[r]; }
            #pragma unroll
            for (int kt = 0; kt < 4; ++kt) {
                az = __builtin_amdgcn_mfma_f32_16x16x32_bf16(wfrag[0][kt], hfrag[kt], az, 0, 0, 0);
                ar = __builtin_amdgcn_mfma_f32_16x16x32_bf16(wfrag[1][kt], hfrag[kt], ar, 0, 0, 0);
                an = __builtin_amdgcn_mfma_f32_16x16x32_bf16(wfrag[2][kt], hfrag[kt], an, 0, 0, 0);
            }
            // consume this step's xg (loaded 2 steps ago)
            float xzv[4], xrv[4], xnv[4];
            #pragma unroll
            for (int r = 0; r < 4; ++r) {
                xzv[r] = bfbits2f(xs[u][0][r]);
                xrv[r] = bfbits2f(xs[u][1][r]);
                xnv[r] = bfbits2f(xs[u][2][r]);
            }
            // prefetch t+2 into slot u (clamped at tail; harmless duplicate)
            {
                const int sn = (step + 2 < T) ? step + 2 : step;
                const int tn = dir ? (T-1-sn) : sn;
                const size_t ro = ((size_t)brow*T + tn)*G3;
                xs[u][0] = *reinterpret_cast<const ushort4_t*>(&xg[ro +       cb]);
                xs[u][1] = *reinterpret_cast<const ushort4_t*>(&xg[ro + U   + cb]);
                xs[u][2] = *reinterpret_cast<const ushort4_t*>(&xg[ro + 2*U + cb]);
            }
            // gates + state update (batch brow, cols cb..cb+3)
            ushort4_t hpk;
            #pragma unroll
            for (int r = 0; r < 4; ++r) {
                const float z  = sigmoidf_(xzv[r] + az[r]);
                const float rr = sigmoidf_(xrv[r] + ar[r]);
                const float n  = tanhf_(xnv[r] + rr*an[r]);
                const float hnew = z*hprev[r] + (1.0f - z)*n;
                hprev[r] = hnew;
                bf16 hb = __float2bfloat16(hnew);
                hpk[r] = *reinterpret_cast<unsigned short*>(&hb);
            }
            // contiguous b64 LDS write into next-parity buffer
            *reinterpret_cast<ushort4_t*>(&hbuf[u^1][l16*136 + cb]) = hpk;
            // yseq store (b64); never waited in-loop (no vmcnt drain at barrier)
            if (yseq)
                *reinterpret_cast<ushort4_t*>(
                    &yseq[((size_t)brow*T + t)*M2 + dir*U + cb]) = hpk;
            // LDS-only barrier: wait lgkmcnt(0), leave vmcnt in flight
            asm volatile("" ::: "memory");
            __builtin_amdgcn_s_waitcnt(0xC07F);
            __builtin_amdgcn_s_barrier();
            asm volatile("" ::: "memory");
        }
    }
    if (hout) {
        float4 hv = make_float4(hprev[0], hprev[1], hprev[2], hprev[3]);
        *reinterpret_cast<float4*>(&hout[(size_t)brow*M2 + dir*U + cb]) = hv;
    }
}

// ---------------- MFMA flash attention ----------------
// Q,K,O: [B*T, HD] bf16 (head h at col h*KD). VT: [HD, B*T] bf16 (transposed V).
__global__ __launch_bounds__(256) void k_attn(const bf16* __restrict__ Q,
        const bf16* __restrict__ Kp, const bf16* __restrict__ VT,
        bf16* __restrict__ O)
{
    __shared__ short k_s[64*136];    // 17408 B
    __shared__ short vt_s[128*72];   // 18432 B
    __shared__ short p_s[64*72];     //  9216 B
    const int qt = blockIdx.x;       // 0..7
    const int b  = blockIdx.y;
    const int h  = blockIdx.z;
    const int tid  = threadIdx.x;
    const int lane = tid & 63;
    const int wv   = tid >> 6;
    const int l16  = lane & 15;
    const int quad = lane >> 4;

    short8 qfrag[4];
    {
        const size_t qoff = (size_t)(b*T + qt*64 + wv*16 + l16)*HD + h*KD + quad*8;
        #pragma unroll
        for (int kt = 0; kt < 4; ++kt)
            qfrag[kt] = *reinterpret_cast<const short8*>(&Q[qoff + kt*32]);
    }

    floatx4 Oa[8];
    #pragma unroll
    for (int nf = 0; nf < 8; ++nf) Oa[nf] = (floatx4)0.0f;
    float mrun = -1e30f, lrun = 0.0f;

    for (int kg = 0; kg < 8; ++kg) {
        __syncthreads();
        #pragma unroll
        for (int it = 0; it < 4; ++it) {
            const int linear = it*256 + tid;
            const int key = linear >> 4;
            const int dc  = linear & 15;
            const float4 v = *reinterpret_cast<const float4*>(
                &Kp[(size_t)(b*T + kg*64 + key)*HD + h*KD + dc*8]);
            *reinterpret_cast<float4*>(&k_s[key*136 + dc*8]) = v;
        }
        #pragma unroll
        for (int it = 0; it < 4; ++it) {
            const int linear = it*256 + tid;
            const int d  = linear >> 3;
            const int kc = linear & 7;
            const float4 v = *reinterpret_cast<const float4*>(
                &VT[(size_t)(h*KD + d)*BT + b*T + kg*64 + kc*8]);
            *reinterpret_cast<float4*>(&vt_s[d*72 + kc*8]) = v;
        }
        __syncthreads();
        floatx4 s[4];
        #pragma unroll
        for (int kb = 0; kb < 4; ++kb) s[kb] = (floatx4)0.0f;
        #pragma unroll
        for (int kt = 0; kt < 4; ++kt) {
            #pragma unroll
            for (int kb = 0; kb < 4; ++kb) {
                const short8 af = *reinterpret_cast<const short8*>(
                    &k_s[(kb*16 + l16)*136 + kt*32 + quad*8]);
                s[kb] = __builtin_amdgcn_mfma_f32_16x16x32_bf16(af, qfrag[kt], s[kb], 0, 0, 0);
            }
        }
        float kmax = -1e30f;
        #pragma unroll
        for (int kb = 0; kb < 4; ++kb)
            #pragma unroll
            for (int r = 0; r < 4; ++r) {
                s[kb][r] *= 0.08838834764831845f;
                kmax = fmaxf(kmax, s[kb][r]);
            }
        kmax = fmaxf(kmax, __shfl_xor(kmax, 16));
        kmax = fmaxf(kmax, __shfl_xor(kmax, 32));
        const float mnew  = fmaxf(mrun, kmax);
        const float alpha = __expf(mrun - mnew);
        float psum = 0.0f;
        #pragma unroll
        for (int kb = 0; kb < 4; ++kb)
            #pragma unroll
            for (int r = 0; r < 4; ++r) {
                const float p = __expf(s[kb][r] - mnew);
                s[kb][r] = p;
                psum += p;
            }
        psum += __shfl_xor(psum, 16);
        psum += __shfl_xor(psum, 32);
        lrun = lrun*alpha + psum;
        mrun = mnew;
        #pragma unroll
        for (int r = 0; r < 4; ++r) {
            const float ar = __shfl(alpha, quad*4 + r);
            #pragma unroll
            for (int nf = 0; nf < 8; ++nf) Oa[nf][r] *= ar;
        }
        bf16* pb = reinterpret_cast<bf16*>(p_s);
        #pragma unroll
        for (int kb = 0; kb < 4; ++kb)
            #pragma unroll
            for (int r = 0; r < 4; ++r)
                pb[(wv*16 + l16)*72 + kb*16 + quad*4 + r] = __float2bfloat16(s[kb][r]);
        #pragma unroll
        for (int kt2 = 0; kt2 < 2; ++kt2) {
            const short8 pf = *reinterpret_cast<const short8*>(
                &p_s[(wv*16 + l16)*72 + kt2*32 + quad*8]);
            #pragma unroll
            for (int nf = 0; nf < 8; ++nf) {
                const short8 vf = *reinterpret_cast<const short8*>(
                    &vt_s[(nf*16 + l16)*72 + kt2*32 + quad*8]);
                Oa[nf] = __builtin_amdgcn_mfma_f32_16x16x32_bf16(pf, vf, Oa[nf], 0, 0, 0);
            }
        }
    }
    float linv[4];
    #pragma unroll
    for (int r = 0; r < 4; ++r) linv[r] = 1.0f / __shfl(lrun, quad*4 + r);
    #pragma unroll
    for (int nf = 0; nf < 8; ++nf)
        #pragma unroll
        for (int r = 0; r < 4; ++r) {
            const size_t row = (size_t)(b*T + qt*64 + wv*16 + quad*4 + r);
            O[row*HD + h*KD + nf*16 + l16] = __float2bfloat16(Oa[nf][r] * linv[r]);
        }
}

// ---------------- dense head ----------------
__global__ void k_dense(const float* __restrict__ h2, const float* __restrict__ dw,
                        const float* __restrict__ db, float* __restrict__ out)
{
    const int b = threadIdx.x;
    float acc = db[0];
    for (int mm = 0; mm < M2; ++mm) acc += h2[b*M2 + mm] * dw[mm];
    out[b] = acc;
}

extern "C" void kernel_launch(void* const* d_in, const int* in_sizes, int n_in,
                              void* d_out, int out_size, void* d_ws, size_t ws_size,
                              hipStream_t stream)
{
    const float* inputs  = (const float*)d_in[0];
    const float* conv_w  = (const float*)d_in[1];
    const float* conv_b  = (const float*)d_in[2];
    const float* bn_g    = (const float*)d_in[3];
    const float* bn_b    = (const float*)d_in[4];
    const float* bn_m    = (const float*)d_in[5];
    const float* bn_v    = (const float*)d_in[6];
    const float* g1f_wx  = (const float*)d_in[7];
    const float* g1f_wh  = (const float*)d_in[8];
    const float* g1f_b   = (const float*)d_in[9];
    const float* g1b_wx  = (const float*)d_in[10];
    const float* g1b_wh  = (const float*)d_in[11];
    const float* g1b_b   = (const float*)d_in[12];
    const float* wq      = (const float*)d_in[13];
    const float* bq      = (const float*)d_in[14];
    const float* wk      = (const float*)d_in[15];
    const float* bk      = (const float*)d_in[16];
    const float* wv_     = (const float*)d_in[17];
    const float* bv      = (const float*)d_in[18];
    const float* wo      = (const float*)d_in[19];
    const float* bo      = (const float*)d_in[20];
    const float* g2f_wx  = (const float*)d_in[21];
    const float* g2f_wh  = (const float*)d_in[22];
    const float* g2f_b   = (const float*)d_in[23];
    const float* g2b_wx  = (const float*)d_in[24];
    const float* g2b_wh  = (const float*)d_in[25];
    const float* g2b_b   = (const float*)d_in[26];
    const float* dense_w = (const float*)d_in[27];
    const float* dense_b = (const float*)d_in[28];
    float* out = (float*)d_out;
    (void)in_sizes; (void)n_in; (void)out_size; (void)ws_size;

    // ---- workspace (float-slot offsets into 128 MiB = 33,554,432 fslots) ----
    float* ws = (float*)d_ws;
    bf16* wb = (bf16*)ws;
    bf16* g1fT = wb;            // [384,64]
    bf16* g1bT = wb + 24576;
    bf16* wqT  = wb + 49152;    // [512,256]
    bf16* wkT  = wb + 180224;
    bf16* wvT  = wb + 311296;   // [512,256] -> GEMM-A for V^T
    bf16* woT  = wb + 442368;   // [256,512]
    bf16* g2fT = wb + 573440;   // [384,256]
    bf16* g2bT = wb + 671744;   // ends 770048 < 786432

    bf16*  x1h  = (bf16*)(ws + 393216);     // [B*T,64]
    bf16*  xg1f = (bf16*)(ws + 1441792);    // [B*T,384] bf16 (6.29M fslots)
    bf16*  xg1b = (bf16*)(ws + 7733248);    // [B*T,384] bf16 (ends 14024704)
    bf16*  y1h  = (bf16*)(ws + 26607616);   // [B*T,256]
    bf16*  qh   = (bf16*)(ws + 393216);     // [B*T,512]
    bf16*  kh   = (bf16*)(ws + 8781824);    // [B*T,512]
    bf16*  vtg  = (bf16*)(ws + 17170432);   // [512, B*T]
    bf16*  Oh   = qh;                       // attention output in-place
    bf16*  x2h  = (bf16*)(ws + 17170432);   // [B*T,256] (over dead vtg)
    bf16*  xg2f = (bf16*)(ws + 393216);     // [B*T,384]
    bf16*  xg2b = (bf16*)(ws + 6684672);
    float* h2   = ws + 12976128;            // [B,256]

    // 0. weight casts
    k_wcast<<<(64*384+255)/256, 256, 0, stream>>>(g1f_wx, g1fT, 64, 384);
    k_wcast<<<(64*384+255)/256, 256, 0, stream>>>(g1b_wx, g1bT, 64, 384);
    k_wcast<<<(256*512+255)/256, 256, 0, stream>>>(wq,  wqT, 256, 512);
    k_wcast<<<(256*512+255)/256, 256, 0, stream>>>(wk,  wkT, 256, 512);
    k_wcast<<<(256*512+255)/256, 256, 0, stream>>>(wv_, wvT, 256, 512);
    k_wcast<<<(512*256+255)/256, 256, 0, stream>>>(wo,  woT, 512, 256);
    k_wcast<<<(256*384+255)/256, 256, 0, stream>>>(g2f_wx, g2fT, 256, 384);
    k_wcast<<<(256*384+255)/256, 256, 0, stream>>>(g2b_wx, g2bT, 256, 384);

    // 1. conv + BN + ReLU -> x1h
    k_conv<<<dim3(T/16, B), 256, 0, stream>>>(inputs, conv_w, conv_b,
                                              bn_g, bn_b, bn_m, bn_v, x1h);
    // 2. GRU1 input gates (bf16)
    k_gemm<<<dim3(3, 256), 256, 0, stream>>>(x1h, g1fT, g1f_b, nullptr, nullptr, xg1f, 64, G3, 0);
    k_gemm<<<dim3(3, 256), 256, 0, stream>>>(x1h, g1bT, g1b_b, nullptr, nullptr, xg1b, 64, G3, 0);
    // 3. GRU1 scan -> y1h  (transposed MFMA, 8 blocks x 512)
    k_gru<<<dim3(4, 2), 512, 0, stream>>>(xg1f, xg1b, g1f_wh, g1b_wh,
                                          g1f_b, g1b_b, y1h, nullptr);
    // 4. Q,K projections; V as transposed GEMM
    k_gemm<<<dim3(4, 256), 256, 0, stream>>>(y1h, wqT, bq, nullptr, nullptr, qh, 256, HD, 0);
    k_gemm<<<dim3(4, 256), 256, 0, stream>>>(y1h, wkT, bk, nullptr, nullptr, kh, 256, HD, 0);
    k_gemm<<<dim3(BT/128, 4), 256, 0, stream>>>(wvT, y1h, bv, nullptr, nullptr, vtg, 256, BT, 1);
    // 5. MFMA flash attention, O in-place over Q
    k_attn<<<dim3(T/64, B, NH), 256, 0, stream>>>(qh, kh, vtg, Oh);
    // 6. output projection + bias + residual(y1h) -> x2h
    k_gemm<<<dim3(2, 256), 256, 0, stream>>>(Oh, woT, bo, y1h, nullptr, x2h, HD, M2, 0);
    // 7. GRU2 input gates (bf16)
    k_gemm<<<dim3(3, 256), 256, 0, stream>>>(x2h, g2fT, g2f_b, nullptr, nullptr, xg2f, 256, G3, 0);
    k_gemm<<<dim3(3, 256), 256, 0, stream>>>(x2h, g2bT, g2b_b, nullptr, nullptr, xg2b, 256, G3, 0);
    // 8. GRU2 scan -> h2
    k_gru<<<dim3(4, 2), 512, 0, stream>>>(xg2f, xg2b, g2f_wh, g2b_wh,
                                          g2f_b, g2b_b, nullptr, h2);
    // 9. dense head
    k_dense<<<1, 64, 0, stream>>>(h2, dense_w, dense_b, out);
}